// Round 1
// baseline (106.906 us; speedup 1.0000x reference)
//
#include <hip/hip_runtime.h>
#include <hip/hip_bf16.h>

// Problem constants (fixed by the reference).
#define M_ROWS 8192
#define K_DIM 128
#define NBINS 64            // label bins (labels 0..19; padded pow2, masked)
#define NCHUNK 8            // column-range splits across the grid
#define NRB 128             // M / 64 row-blocks
#define TILES_PER_CHUNK 8   // (8192/NCHUNK)/128 col tiles per chunk
#define NPART (NCHUNK * 2)  // partial (m,s) sets per row: chunks x 2 col-waves

typedef __attribute__((ext_vector_type(8))) short bf16x8;
typedef __attribute__((ext_vector_type(4))) float f32x4;

// Workspace layout (bytes). Total ~3.2 MB.
#define FB16_OFF 0
#define PM_OFF (M_ROWS * K_DIM * 2)            // 2 MB of bf16 features
#define PS_OFF (PM_OFF + NPART * M_ROWS * 4)   // +512 KB partial max
#define CNT_OFF (PS_OFF + NPART * M_ROWS * 4)  // +512 KB partial sum
#define SUM_OFF (CNT_OFF + NBINS * 4)

__device__ __forceinline__ unsigned short f2bf(float f) {
  union { float f; unsigned int u; } v;
  v.f = f;
  unsigned int r = v.u + 0x7FFFu + ((v.u >> 16) & 1u);  // RNE
  return (unsigned short)(r >> 16);
}

__global__ void k_zero(float* __restrict__ sums, int* __restrict__ cnt) {
  const int t = threadIdx.x;
  if (t < NBINS) cnt[t] = 0;
  if (t < 2) sums[t] = 0.f;
}

__global__ void k_hist(const int* __restrict__ labels, int* __restrict__ cnt) {
  __shared__ int h[NBINS];
  const int t = threadIdx.x;
  if (t < NBINS) h[t] = 0;
  __syncthreads();
  const int i = blockIdx.x * 256 + t;
  atomicAdd(&h[labels[i] & (NBINS - 1)], 1);
  __syncthreads();
  if (t < NBINS && h[t]) atomicAdd(&cnt[t], h[t]);
}

__global__ void k_convert(const float* __restrict__ src,
                          unsigned short* __restrict__ dst) {
  const int i = (blockIdx.x * 256 + threadIdx.x) * 4;
  const float4 v = *reinterpret_cast<const float4*>(&src[i]);
  ushort4 o;
  o.x = f2bf(v.x);
  o.y = f2bf(v.y);
  o.z = f2bf(v.z);
  o.w = f2bf(v.w);
  *reinterpret_cast<ushort4*>(&dst[i]) = o;
}

// Fused sim + online masked exp-sum. Block = 4 waves (2 row-waves x 2
// col-waves); wave tile = 32 rows x 64 cols per 128-col tile; K=128 held in
// registers as 8 bf16x8 A-fragments. Grid = NRB row-blocks x NCHUNK col-chunks.
__global__ __launch_bounds__(256) void k_main(
    const unsigned short* __restrict__ fb16, const int* __restrict__ labels,
    float* __restrict__ pm, float* __restrict__ ps) {
  const int tid = threadIdx.x;
  const int lane = tid & 63;
  const int wid = tid >> 6;
  const int wr = wid >> 1;
  const int wc = wid & 1;
  const int rb = (int)blockIdx.x % NRB;
  const int chunk = (int)blockIdx.x / NRB;
  const int l15 = lane & 15;
  const int lhi = lane >> 4;
  const int row0 = rb * 64 + wr * 32;

  // A fragments: lane holds A[l&15][(l>>4)*8 + e] for each 16x32 k-slice.
  bf16x8 a[2][4];
#pragma unroll
  for (int ri = 0; ri < 2; ++ri) {
    const int row = row0 + ri * 16 + l15;
#pragma unroll
    for (int ks = 0; ks < 4; ++ks)
      a[ri][ks] = *reinterpret_cast<const bf16x8*>(
          &fb16[row * K_DIM + ks * 32 + lhi * 8]);
  }

  // Row labels for the 8 output rows this lane's accumulators touch
  // (C/D layout: row = (lane>>4)*4 + reg, col = lane&15).
  int rlab[2][4];
#pragma unroll
  for (int ri = 0; ri < 2; ++ri)
#pragma unroll
    for (int rg = 0; rg < 4; ++rg)
      rlab[ri][rg] = labels[row0 + ri * 16 + lhi * 4 + rg];

  float m_st[2][4], s_st[2][4];
#pragma unroll
  for (int ri = 0; ri < 2; ++ri)
#pragma unroll
    for (int rg = 0; rg < 4; ++rg) {
      m_st[ri][rg] = -INFINITY;
      s_st[ri][rg] = 0.f;
    }

  const f32x4 vzero = {0.f, 0.f, 0.f, 0.f};

  for (int t = 0; t < TILES_PER_CHUNK; ++t) {
    const int colT = chunk * 1024 + t * 128 + wc * 64;
    int clab[4];
#pragma unroll
    for (int cj = 0; cj < 4; ++cj) clab[cj] = labels[colT + cj * 16 + l15];

    f32x4 acc[2][4];
#pragma unroll
    for (int ri = 0; ri < 2; ++ri)
#pragma unroll
      for (int cj = 0; cj < 4; ++cj) acc[ri][cj] = vzero;

#pragma unroll
    for (int ks = 0; ks < 4; ++ks) {
      bf16x8 b[4];
#pragma unroll
      for (int cj = 0; cj < 4; ++cj) {
        const int crow = colT + cj * 16 + l15;
        b[cj] = *reinterpret_cast<const bf16x8*>(
            &fb16[crow * K_DIM + ks * 32 + lhi * 8]);
      }
#pragma unroll
      for (int ri = 0; ri < 2; ++ri)
#pragma unroll
        for (int cj = 0; cj < 4; ++cj)
          acc[ri][cj] = __builtin_amdgcn_mfma_f32_16x16x32_bf16(
              a[ri][ks], b[cj], acc[ri][cj], 0, 0, 0);
    }

    // Online masked exp-sum epilogue. Row r's 64 elements live in 16
    // consecutive lanes (same lane>>4) x 4 col fragments.
#pragma unroll
    for (int ri = 0; ri < 2; ++ri) {
#pragma unroll
      for (int rg = 0; rg < 4; ++rg) {
        const float sc0 = acc[ri][0][rg] * 5.0f;  // 1/TEMPERATURE
        const float sc1 = acc[ri][1][rg] * 5.0f;
        const float sc2 = acc[ri][2][rg] * 5.0f;
        const float sc3 = acc[ri][3][rg] * 5.0f;
        float tmax = fmaxf(fmaxf(sc0, sc1), fmaxf(sc2, sc3));
        tmax = fmaxf(tmax, __shfl_xor(tmax, 1));
        tmax = fmaxf(tmax, __shfl_xor(tmax, 2));
        tmax = fmaxf(tmax, __shfl_xor(tmax, 4));
        tmax = fmaxf(tmax, __shfl_xor(tmax, 8));
        const float mo = m_st[ri][rg];
        const float mn = fmaxf(mo, tmax);
        // If the whole tile sits >104 below the running max, every exp term
        // underflows past f32 denormals -> contributes exact 0; skip.
        if (tmax - mn >= -104.0f) {
          const int rl = rlab[ri][rg];
          float p = 0.f;
          p += (clab[0] != rl) ? __expf(sc0 - mn) : 0.f;
          p += (clab[1] != rl) ? __expf(sc1 - mn) : 0.f;
          p += (clab[2] != rl) ? __expf(sc2 - mn) : 0.f;
          p += (clab[3] != rl) ? __expf(sc3 - mn) : 0.f;
          p += __shfl_xor(p, 1);
          p += __shfl_xor(p, 2);
          p += __shfl_xor(p, 4);
          p += __shfl_xor(p, 8);
          s_st[ri][rg] = s_st[ri][rg] * __expf(mo - mn) + p;
          m_st[ri][rg] = mn;
        }
      }
    }
  }

  // One lane per 16-lane row-group writes the partial (m, s).
  if (l15 == 0) {
    const int part = chunk * 2 + wc;
#pragma unroll
    for (int ri = 0; ri < 2; ++ri)
#pragma unroll
      for (int rg = 0; rg < 4; ++rg) {
        const int row = row0 + ri * 16 + lhi * 4 + rg;
        pm[part * M_ROWS + row] = m_st[ri][rg];
        ps[part * M_ROWS + row] = s_st[ri][rg];
      }
  }
}

__global__ __launch_bounds__(256) void k_merge(
    const float* __restrict__ pm, const float* __restrict__ ps,
    const int* __restrict__ cnt, const int* __restrict__ labels,
    const float* __restrict__ ious, float* __restrict__ sums) {
  const int row = blockIdx.x * 256 + threadIdx.x;
  float gm = -INFINITY;
#pragma unroll
  for (int p = 0; p < NPART; ++p) gm = fmaxf(gm, pm[p * M_ROWS + row]);
  float ns = 0.f;
#pragma unroll
  for (int p = 0; p < NPART; ++p)
    ns += ps[p * M_ROWS + row] * __expf(pm[p * M_ROWS + row] - gm);
  int pc = cnt[labels[row] & (NBINS - 1)] - 1;
  if (pc < 1) pc = 1;  // reference always has pos_cnt>=1 here; avoid 0/0
  const float loss = ns / (float)pc;  // LAMDA = 1; loss = -log_prob
  const bool keep = ious[row] >= 0.5f;
  float lv = keep ? loss : 0.f;
  float kv = keep ? 1.f : 0.f;
#pragma unroll
  for (int off = 32; off >= 1; off >>= 1) {
    lv += __shfl_xor(lv, off);
    kv += __shfl_xor(kv, off);
  }
  __shared__ float slv[4], skv[4];
  const int lane = threadIdx.x & 63, wv = threadIdx.x >> 6;
  if (lane == 0) {
    slv[wv] = lv;
    skv[wv] = kv;
  }
  __syncthreads();
  if (threadIdx.x == 0) {
    atomicAdd(&sums[0], slv[0] + slv[1] + slv[2] + slv[3]);
    atomicAdd(&sums[1], skv[0] + skv[1] + skv[2] + skv[3]);
  }
}

__global__ void k_final(const float* __restrict__ sums,
                        float* __restrict__ out) {
  out[0] = sums[0] / fmaxf(sums[1], 1.0f);
}

extern "C" void kernel_launch(void* const* d_in, const int* in_sizes, int n_in,
                              void* d_out, int out_size, void* d_ws,
                              size_t ws_size, hipStream_t stream) {
  const float* feat = (const float*)d_in[0];
  const int* labels = (const int*)d_in[1];
  const float* ious = (const float*)d_in[2];
  float* out = (float*)d_out;
  char* ws = (char*)d_ws;
  unsigned short* fb16 = (unsigned short*)(ws + FB16_OFF);
  float* pm = (float*)(ws + PM_OFF);
  float* ps = (float*)(ws + PS_OFF);
  int* cnt = (int*)(ws + CNT_OFF);
  float* sums = (float*)(ws + SUM_OFF);

  hipLaunchKernelGGL(k_zero, dim3(1), dim3(64), 0, stream, sums, cnt);
  hipLaunchKernelGGL(k_hist, dim3(M_ROWS / 256), dim3(256), 0, stream, labels,
                     cnt);
  hipLaunchKernelGGL(k_convert, dim3(M_ROWS * K_DIM / 1024), dim3(256), 0,
                     stream, feat, fb16);
  hipLaunchKernelGGL(k_main, dim3(NRB * NCHUNK), dim3(256), 0, stream, fb16,
                     labels, pm, ps);
  hipLaunchKernelGGL(k_merge, dim3(M_ROWS / 256), dim3(256), 0, stream, pm, ps,
                     cnt, labels, ious, sums);
  hipLaunchKernelGGL(k_final, dim3(1), dim3(1), 0, stream, sums, out);
}

// Round 2
// 54.278 us; speedup vs baseline: 1.9696x; 1.9696x over previous
//
#include <hip/hip_runtime.h>
#include <hip/hip_bf16.h>

// Problem constants (fixed by the reference).
#define M_ROWS 8192
#define K_DIM 128
#define NBINS 64           // label bins (labels 0..19; padded pow2, masked)
#define NCHUNK 8           // column-range splits across the grid
#define NRB2 64            // M / 128 row-blocks
#define TILES_PER_CHUNK 8  // 1024-col chunk / 128-col tiles
#define NPART (NCHUNK * 2) // partial sums per row: chunks x 2 col-waves

// C = 5 * log2(e): score in log2 domain is acc * C. exp(sim - m) = exp2(acc*C - m2).
#define C_LOG2 7.213475204444817f
#define INV_C 0.1386294361119891f
#define FLUSH_THR 160.0f  // exp2(x) == +0.0f for x < -150; 160 adds margin

typedef __attribute__((ext_vector_type(8))) short bf16x8;
typedef __attribute__((ext_vector_type(4))) float f32x4;

// Workspace layout (bytes). Total ~2.6 MB.
#define FB16_OFF 0
#define RN2_OFF (M_ROWS * K_DIM * 2)         // 2 MB bf16 features
#define PS_OFF (RN2_OFF + M_ROWS * 4)        // +32 KB row-seed (log2 domain)
#define CNT_OFF (PS_OFF + NPART * M_ROWS * 4)
#define SUM_OFF (CNT_OFF + NBINS * 4)

__device__ __forceinline__ unsigned short f2bf(float f) {
  union { float f; unsigned int u; } v;
  v.f = f;
  unsigned int r = v.u + 0x7FFFu + ((v.u >> 16) & 1u);  // RNE
  return (unsigned short)(r >> 16);
}

__global__ void k_zero(float* __restrict__ sums, int* __restrict__ cnt) {
  const int t = threadIdx.x;
  if (t < NBINS) cnt[t] = 0;
  if (t < 2) sums[t] = 0.f;
}

__global__ void k_hist(const int* __restrict__ labels, int* __restrict__ cnt) {
  __shared__ int h[NBINS];
  const int t = threadIdx.x;
  if (t < NBINS) h[t] = 0;
  __syncthreads();
  const int i = blockIdx.x * 256 + t;
  atomicAdd(&h[labels[i] & (NBINS - 1)], 1);
  __syncthreads();
  if (t < NBINS && h[t]) atomicAdd(&cnt[t], h[t]);
}

// f32 -> bf16 convert fused with row-norm seed: rn2[i] = C * ||f_i||^2
// (the diagonal score in log2 domain). One wave handles 2 rows; 32 lanes/row,
// float4 per lane.
__global__ __launch_bounds__(256) void k_convert(const float* __restrict__ src,
                                                 unsigned short* __restrict__ dst,
                                                 float* __restrict__ rn2) {
  const int wid = threadIdx.x >> 6;
  const int lane = threadIdx.x & 63;
  const int half = lane >> 5;
  const int l5 = lane & 31;
  const int row = blockIdx.x * 8 + wid * 2 + half;
  const int base = row * K_DIM + l5 * 4;
  const float4 v = *reinterpret_cast<const float4*>(&src[base]);
  ushort4 o;
  o.x = f2bf(v.x);
  o.y = f2bf(v.y);
  o.z = f2bf(v.z);
  o.w = f2bf(v.w);
  *reinterpret_cast<ushort4*>(&dst[base]) = o;
  float sq = v.x * v.x + v.y * v.y + v.z * v.z + v.w * v.w;
  sq += __shfl_xor(sq, 1);
  sq += __shfl_xor(sq, 2);
  sq += __shfl_xor(sq, 4);
  sq += __shfl_xor(sq, 8);
  sq += __shfl_xor(sq, 16);
  if (l5 == 0) rn2[row] = sq * C_LOG2;
}

// Fused sim + masked exp-sum with fixed per-row seed m = rn2[row].
// Block = 4 waves (2 row x 2 col); wave tile = 64 rows x 64 cols per 128-col
// tile; 8 tiles over a 1024-col chunk. Grid = NRB2 x NCHUNK = 512 blocks.
// No cross-lane ops in the tile loop: a per-lane max vs. flush threshold
// decides (honestly, per data) whether any exp term can be nonzero.
__global__ __launch_bounds__(256, 2) void k_main(
    const unsigned short* __restrict__ fb16, const int* __restrict__ labels,
    const float* __restrict__ rn2, float* __restrict__ ps) {
  const int tid = threadIdx.x;
  const int lane = tid & 63;
  const int wid = tid >> 6;
  const int wr = wid >> 1;
  const int wc = wid & 1;
  const int rb = (int)blockIdx.x % NRB2;
  const int chunk = (int)blockIdx.x / NRB2;
  const int l15 = lane & 15;
  const int lhi = lane >> 4;
  const int row0 = rb * 128 + wr * 64;

  // A fragments: lane holds A[l&15][(l>>4)*8 + e] per 16x32 k-slice.
  bf16x8 a[4][4];
#pragma unroll
  for (int ri = 0; ri < 4; ++ri) {
    const int row = row0 + ri * 16 + l15;
#pragma unroll
    for (int ks = 0; ks < 4; ++ks)
      a[ri][ks] = *reinterpret_cast<const bf16x8*>(
          &fb16[row * K_DIM + ks * 32 + lhi * 8]);
  }

  // Flush threshold in acc domain: skip a tile when every acc value of this
  // lane is below (rn2[row] - 160)/C for all of its 16 rows -> every exp2
  // term is exactly +0.0f after subtracting the row seed.
  float thrMin = INFINITY;
#pragma unroll
  for (int ri = 0; ri < 4; ++ri) {
    const float4 v =
        *reinterpret_cast<const float4*>(&rn2[row0 + ri * 16 + lhi * 4]);
    thrMin = fminf(thrMin, fminf(fminf(v.x, v.y), fminf(v.z, v.w)));
  }
  const float thrAcc = (thrMin - FLUSH_THR) * INV_C;

  float s_st[4][4];
#pragma unroll
  for (int ri = 0; ri < 4; ++ri)
#pragma unroll
    for (int rg = 0; rg < 4; ++rg) s_st[ri][rg] = 0.f;

  const f32x4 vzero = {0.f, 0.f, 0.f, 0.f};

  for (int t = 0; t < TILES_PER_CHUNK; ++t) {
    const int colT = chunk * 1024 + t * 128 + wc * 64;

    f32x4 acc[4][4];
#pragma unroll
    for (int ri = 0; ri < 4; ++ri)
#pragma unroll
      for (int cj = 0; cj < 4; ++cj) acc[ri][cj] = vzero;

#pragma unroll
    for (int ks = 0; ks < 4; ++ks) {
      bf16x8 b[4];
#pragma unroll
      for (int cj = 0; cj < 4; ++cj) {
        const int crow = colT + cj * 16 + l15;
        b[cj] = *reinterpret_cast<const bf16x8*>(
            &fb16[crow * K_DIM + ks * 32 + lhi * 8]);
      }
#pragma unroll
      for (int ri = 0; ri < 4; ++ri)
#pragma unroll
        for (int cj = 0; cj < 4; ++cj)
          acc[ri][cj] = __builtin_amdgcn_mfma_f32_16x16x32_bf16(
              a[ri][ks], b[cj], acc[ri][cj], 0, 0, 0);
    }

    // Per-lane flush test (no cross-lane traffic; fmax trees fuse to v_max3).
    float mx = -INFINITY;
#pragma unroll
    for (int ri = 0; ri < 4; ++ri)
#pragma unroll
      for (int cj = 0; cj < 4; ++cj) {
        const f32x4 v = acc[ri][cj];
        mx = fmaxf(mx, fmaxf(fmaxf(v[0], v[1]), fmaxf(v[2], v[3])));
      }

    if (__any(mx >= thrAcc)) {
      // Rare path: tile contains terms that survive the flush (the diagonal
      // tile). Full masked exp2 accumulation against the fixed row seeds.
      int clab[4];
#pragma unroll
      for (int cj = 0; cj < 4; ++cj) clab[cj] = labels[colT + cj * 16 + l15];
#pragma unroll
      for (int ri = 0; ri < 4; ++ri) {
        const float4 ms =
            *reinterpret_cast<const float4*>(&rn2[row0 + ri * 16 + lhi * 4]);
        const int4 rl =
            *reinterpret_cast<const int4*>(&labels[row0 + ri * 16 + lhi * 4]);
        const float msv[4] = {ms.x, ms.y, ms.z, ms.w};
        const int rlv[4] = {rl.x, rl.y, rl.z, rl.w};
#pragma unroll
        for (int rg = 0; rg < 4; ++rg) {
          float p = 0.f;
#pragma unroll
          for (int cj = 0; cj < 4; ++cj) {
            const float sc2 = acc[ri][cj][rg] * C_LOG2 - msv[rg];
            p += (clab[cj] != rlv[rg]) ? exp2f(sc2) : 0.f;
          }
          s_st[ri][rg] += p;
        }
      }
    }
  }

  // One cross-lane reduction per wave, at the end: sum s over the 16 lanes
  // sharing each row group, then lane l15==0 stores float4 per (ri).
#pragma unroll
  for (int ri = 0; ri < 4; ++ri)
#pragma unroll
    for (int rg = 0; rg < 4; ++rg) {
      float p = s_st[ri][rg];
      p += __shfl_xor(p, 1);
      p += __shfl_xor(p, 2);
      p += __shfl_xor(p, 4);
      p += __shfl_xor(p, 8);
      s_st[ri][rg] = p;
    }
  if (l15 == 0) {
    const int part = chunk * 2 + wc;
#pragma unroll
    for (int ri = 0; ri < 4; ++ri) {
      float4 v = {s_st[ri][0], s_st[ri][1], s_st[ri][2], s_st[ri][3]};
      *reinterpret_cast<float4*>(
          &ps[part * M_ROWS + row0 + ri * 16 + lhi * 4]) = v;
    }
  }
}

__global__ __launch_bounds__(256) void k_merge(
    const float* __restrict__ ps, const int* __restrict__ cnt,
    const int* __restrict__ labels, const float* __restrict__ ious,
    float* __restrict__ sums) {
  const int row = blockIdx.x * 256 + threadIdx.x;
  float ns = 0.f;
#pragma unroll
  for (int p = 0; p < NPART; ++p) ns += ps[p * M_ROWS + row];
  int pc = cnt[labels[row] & (NBINS - 1)] - 1;
  if (pc < 1) pc = 1;  // reference always has pos_cnt >= 1 here; avoid 0/0
  const float loss = ns / (float)pc;  // LAMDA = 1; loss = -log_prob
  const bool keep = ious[row] >= 0.5f;
  float lv = keep ? loss : 0.f;
  float kv = keep ? 1.f : 0.f;
#pragma unroll
  for (int off = 32; off >= 1; off >>= 1) {
    lv += __shfl_xor(lv, off);
    kv += __shfl_xor(kv, off);
  }
  __shared__ float slv[4], skv[4];
  const int lane = threadIdx.x & 63, wv = threadIdx.x >> 6;
  if (lane == 0) {
    slv[wv] = lv;
    skv[wv] = kv;
  }
  __syncthreads();
  if (threadIdx.x == 0) {
    atomicAdd(&sums[0], slv[0] + slv[1] + slv[2] + slv[3]);
    atomicAdd(&sums[1], skv[0] + skv[1] + skv[2] + skv[3]);
  }
}

__global__ void k_final(const float* __restrict__ sums,
                        float* __restrict__ out) {
  out[0] = sums[0] / fmaxf(sums[1], 1.0f);
}

extern "C" void kernel_launch(void* const* d_in, const int* in_sizes, int n_in,
                              void* d_out, int out_size, void* d_ws,
                              size_t ws_size, hipStream_t stream) {
  const float* feat = (const float*)d_in[0];
  const int* labels = (const int*)d_in[1];
  const float* ious = (const float*)d_in[2];
  float* out = (float*)d_out;
  char* ws = (char*)d_ws;
  unsigned short* fb16 = (unsigned short*)(ws + FB16_OFF);
  float* rn2 = (float*)(ws + RN2_OFF);
  float* ps = (float*)(ws + PS_OFF);
  int* cnt = (int*)(ws + CNT_OFF);
  float* sums = (float*)(ws + SUM_OFF);

  hipLaunchKernelGGL(k_zero, dim3(1), dim3(64), 0, stream, sums, cnt);
  hipLaunchKernelGGL(k_hist, dim3(M_ROWS / 256), dim3(256), 0, stream, labels,
                     cnt);
  hipLaunchKernelGGL(k_convert, dim3(M_ROWS / 8), dim3(256), 0, stream, feat,
                     fb16, rn2);
  hipLaunchKernelGGL(k_main, dim3(NRB2 * NCHUNK), dim3(256), 0, stream, fb16,
                     labels, rn2, ps);
  hipLaunchKernelGGL(k_merge, dim3(M_ROWS / 256), dim3(256), 0, stream, ps,
                     cnt, labels, ious, sums);
  hipLaunchKernelGGL(k_final, dim3(1), dim3(1), 0, stream, sums, out);
}

// Round 3
// 37.381 us; speedup vs baseline: 2.8599x; 1.4520x over previous
//
#include <hip/hip_runtime.h>
#include <hip/hip_bf16.h>

// Problem constants (fixed by the reference).
#define M_ROWS 8192
#define K_DIM 128
#define NBINS 64           // label bins (labels 0..19; padded pow2, masked)
#define NCHUNK 8           // column-range splits across the grid
#define NRB2 64            // M / 128 row-blocks
#define TILES_PER_CHUNK 8  // 1024-col chunk / 128-col tiles
#define NPART (NCHUNK * 2) // partial sums per row: chunks x 2 col-waves

// C = 5 * log2(e): score in log2 domain is acc * C. exp(sim - m) = exp2(acc*C - m2).
#define C_LOG2 7.213475204444817f
#define INV_C 0.1386294361119891f
#define FLUSH_THR 160.0f  // exp2(x) == +0.0f for x < -150; 160 adds margin

typedef __attribute__((ext_vector_type(8))) short bf16x8;
typedef __attribute__((ext_vector_type(4))) float f32x4;

// Workspace layout (bytes).
#define FB16_OFF 0
#define RN2_OFF (M_ROWS * K_DIM * 2)         // 2 MB bf16 features
#define PS_OFF (RN2_OFF + M_ROWS * 4)        // +32 KB row-seed (log2 domain)
#define CNT_OFF (PS_OFF + NPART * M_ROWS * 4)
#define SUM_OFF (CNT_OFF + NBINS * 4)

__device__ __forceinline__ unsigned short f2bf(float f) {
  union { float f; unsigned int u; } v;
  v.f = f;
  unsigned int r = v.u + 0x7FFFu + ((v.u >> 16) & 1u);  // RNE
  return (unsigned short)(r >> 16);
}

__device__ __forceinline__ void gload_lds16(const unsigned short* g,
                                            unsigned short* l) {
  __builtin_amdgcn_global_load_lds(
      (const __attribute__((address_space(1))) void*)g,
      (__attribute__((address_space(3))) void*)l, 16, 0, 0);
}

// Single-block: label histogram + zero the scalar accumulators.
__global__ __launch_bounds__(256) void k_hist(const int* __restrict__ labels,
                                              int* __restrict__ cnt,
                                              float* __restrict__ sums) {
  __shared__ int h[NBINS];
  const int t = threadIdx.x;
  if (t < NBINS) h[t] = 0;
  __syncthreads();
  for (int j = t; j < M_ROWS; j += 256) atomicAdd(&h[labels[j] & (NBINS - 1)], 1);
  __syncthreads();
  if (t < NBINS) cnt[t] = h[t];
  if (t < 2) sums[t] = 0.f;
}

// f32 -> bf16 convert fused with row-norm seed: rn2[i] = C * ||f_i||^2.
__global__ __launch_bounds__(256) void k_convert(const float* __restrict__ src,
                                                 unsigned short* __restrict__ dst,
                                                 float* __restrict__ rn2) {
  const int wid = threadIdx.x >> 6;
  const int lane = threadIdx.x & 63;
  const int half = lane >> 5;
  const int l5 = lane & 31;
  const int row = blockIdx.x * 8 + wid * 2 + half;
  const int base = row * K_DIM + l5 * 4;
  const float4 v = *reinterpret_cast<const float4*>(&src[base]);
  ushort4 o;
  o.x = f2bf(v.x);
  o.y = f2bf(v.y);
  o.z = f2bf(v.z);
  o.w = f2bf(v.w);
  *reinterpret_cast<ushort4*>(&dst[base]) = o;
  float sq = v.x * v.x + v.y * v.y + v.z * v.z + v.w * v.w;
  sq += __shfl_xor(sq, 1);
  sq += __shfl_xor(sq, 2);
  sq += __shfl_xor(sq, 4);
  sq += __shfl_xor(sq, 8);
  sq += __shfl_xor(sq, 16);
  if (l5 == 0) rn2[row] = sq * C_LOG2;
}

// Fused sim + masked exp-sum, LDS-staged B (2-phase double buffer).
// Block = 4 waves (2 row x 2 col); block tile = 128 rows x 128 cols per step;
// 8 col-tiles per 1024-col chunk. Grid = NRB2 x NCHUNK = 512 blocks.
//
// LDS B-tile layout: logical (col, slot) [slot = 16B k-chunk, 16 slots/row]
// stored at byte col*256 + (slot ^ (col&7))*16. Staged with linear LDS dest +
// inverse-swizzled GLOBAL source (global_load_lds writes base+lane*16), read
// back with the same XOR -> bank-balanced ds_read_b128 (8 cyc, BW floor).
__global__ __launch_bounds__(256, 2) void k_main(
    const unsigned short* __restrict__ fb16, const int* __restrict__ labels,
    const float* __restrict__ rn2, float* __restrict__ ps) {
  __shared__ unsigned short lds[2][128 * 128];  // 2 x 32 KB

  const int tid = threadIdx.x;
  const int lane = tid & 63;
  const int wid = tid >> 6;
  const int wr = wid >> 1;
  const int wc = wid & 1;
  const int rb = (int)blockIdx.x % NRB2;
  const int chunk = (int)blockIdx.x / NRB2;
  const int l15 = lane & 15;
  const int lhi = lane >> 4;
  const int row0 = rb * 128 + wr * 64;
  const int col0 = chunk * 1024;

  // A fragments: lane holds A[l&15][(l>>4)*8 + e] per 16x32 k-slice.
  bf16x8 a[4][4];
#pragma unroll
  for (int ri = 0; ri < 4; ++ri) {
    const int row = row0 + ri * 16 + l15;
#pragma unroll
    for (int ks = 0; ks < 4; ++ks)
      a[ri][ks] = *reinterpret_cast<const bf16x8*>(
          &fb16[row * K_DIM + ks * 32 + lhi * 8]);
  }

  // Flush threshold (acc domain): if every acc < (min rn2 - 160)/C, all exp2
  // terms are exact +0.0f.
  float thrMin = INFINITY;
#pragma unroll
  for (int ri = 0; ri < 4; ++ri) {
    const float4 v =
        *reinterpret_cast<const float4*>(&rn2[row0 + ri * 16 + lhi * 4]);
    thrMin = fminf(thrMin, fminf(fminf(v.x, v.y), fminf(v.z, v.w)));
  }
  const float thrAcc = (thrMin - FLUSH_THR) * INV_C;

  float s_st[4][4];
#pragma unroll
  for (int ri = 0; ri < 4; ++ri)
#pragma unroll
    for (int rg = 0; rg < 4; ++rg) s_st[ri][rg] = 0.f;

  const f32x4 vzero = {0.f, 0.f, 0.f, 0.f};

  // --- Staging: one 128x128 B-tile = 32 instr (8 per wave), 1 KB each.
  // Instruction (wid, it): LDS bytes [wid*8192 + it*1024, +1KB) = cols
  // wid*32+it*4+(lane>>4), phys slot lane&15. Source picks the global slot
  // (lane&15)^(col&7) so the XOR'd read below returns logical order.
#define STAGE(buf, t)                                                        \
  {                                                                          \
    const int colT_ = col0 + (t) * 128;                                      \
    _Pragma("unroll") for (int it = 0; it < 8; ++it) {                       \
      const int col_ = wid * 32 + it * 4 + lhi;                              \
      const int crow_ = colT_ + col_;                                        \
      gload_lds16(&fb16[crow_ * K_DIM + ((l15 ^ (col_ & 7)) << 3)],          \
                  &lds[buf][wid * 4096 + it * 512]);                         \
    }                                                                        \
  }

  STAGE(0, 0);
  asm volatile("s_waitcnt vmcnt(0)" ::: "memory");
  __builtin_amdgcn_s_barrier();

  int cur = 0;
#pragma unroll
  for (int t = 0; t < TILES_PER_CHUNK; ++t) {
    if (t < TILES_PER_CHUNK - 1) STAGE(cur ^ 1, t + 1);

    // Compute on lds[cur].
    f32x4 acc[4][4];
#pragma unroll
    for (int ri = 0; ri < 4; ++ri)
#pragma unroll
      for (int cj = 0; cj < 4; ++cj) acc[ri][cj] = vzero;

    const unsigned short* bufp = &lds[cur][0];
#pragma unroll
    for (int ks = 0; ks < 4; ++ks) {
      bf16x8 b[4];
#pragma unroll
      for (int cj = 0; cj < 4; ++cj) {
        const int col = wc * 64 + cj * 16 + l15;
        const int slot = (ks * 4 + lhi) ^ (col & 7);
        b[cj] = *reinterpret_cast<const bf16x8*>(&bufp[col * 128 + slot * 8]);
      }
#pragma unroll
      for (int ri = 0; ri < 4; ++ri)
#pragma unroll
        for (int cj = 0; cj < 4; ++cj)
          acc[ri][cj] = __builtin_amdgcn_mfma_f32_16x16x32_bf16(
              a[ri][ks], b[cj], acc[ri][cj], 0, 0, 0);
    }

    // Per-lane flush test (fmax trees fuse to v_max3; no cross-lane traffic).
    float mx = -INFINITY;
#pragma unroll
    for (int ri = 0; ri < 4; ++ri)
#pragma unroll
      for (int cj = 0; cj < 4; ++cj) {
        const f32x4 v = acc[ri][cj];
        mx = fmaxf(mx, fmaxf(fmaxf(v[0], v[1]), fmaxf(v[2], v[3])));
      }

    if (__any(mx >= thrAcc)) {
      // Rare path (diagonal tile): full masked exp2 against fixed row seeds.
      const int colT = col0 + t * 128 + wc * 64;
      int clab[4];
#pragma unroll
      for (int cj = 0; cj < 4; ++cj) clab[cj] = labels[colT + cj * 16 + l15];
#pragma unroll
      for (int ri = 0; ri < 4; ++ri) {
        const float4 ms =
            *reinterpret_cast<const float4*>(&rn2[row0 + ri * 16 + lhi * 4]);
        const int4 rl =
            *reinterpret_cast<const int4*>(&labels[row0 + ri * 16 + lhi * 4]);
        const float msv[4] = {ms.x, ms.y, ms.z, ms.w};
        const int rlv[4] = {rl.x, rl.y, rl.z, rl.w};
#pragma unroll
        for (int rg = 0; rg < 4; ++rg) {
          float p = 0.f;
#pragma unroll
          for (int cj = 0; cj < 4; ++cj) {
            const float sc2 = acc[ri][cj][rg] * C_LOG2 - msv[rg];
            p += (clab[cj] != rlv[rg]) ? exp2f(sc2) : 0.f;
          }
          s_st[ri][rg] += p;
        }
      }
    }

    // One barrier per tile: drains this iter's stage (issued ~a tile of
    // compute ago) and fences buffer reuse for the next iteration.
    asm volatile("s_waitcnt vmcnt(0)" ::: "memory");
    __builtin_amdgcn_s_barrier();
    cur ^= 1;
  }

  // One cross-lane reduction per wave at the end.
#pragma unroll
  for (int ri = 0; ri < 4; ++ri)
#pragma unroll
    for (int rg = 0; rg < 4; ++rg) {
      float p = s_st[ri][rg];
      p += __shfl_xor(p, 1);
      p += __shfl_xor(p, 2);
      p += __shfl_xor(p, 4);
      p += __shfl_xor(p, 8);
      s_st[ri][rg] = p;
    }
  if (l15 == 0) {
    const int part = chunk * 2 + wc;
#pragma unroll
    for (int ri = 0; ri < 4; ++ri) {
      float4 v = {s_st[ri][0], s_st[ri][1], s_st[ri][2], s_st[ri][3]};
      *reinterpret_cast<float4*>(
          &ps[part * M_ROWS + row0 + ri * 16 + lhi * 4]) = v;
    }
  }
}

__global__ __launch_bounds__(256) void k_merge(
    const float* __restrict__ ps, const int* __restrict__ cnt,
    const int* __restrict__ labels, const float* __restrict__ ious,
    float* __restrict__ sums) {
  const int row = blockIdx.x * 256 + threadIdx.x;
  float ns = 0.f;
#pragma unroll
  for (int p = 0; p < NPART; ++p) ns += ps[p * M_ROWS + row];
  int pc = cnt[labels[row] & (NBINS - 1)] - 1;
  if (pc < 1) pc = 1;  // reference always has pos_cnt >= 1 here; avoid 0/0
  const float loss = ns / (float)pc;  // LAMDA = 1; loss = -log_prob
  const bool keep = ious[row] >= 0.5f;
  float lv = keep ? loss : 0.f;
  float kv = keep ? 1.f : 0.f;
#pragma unroll
  for (int off = 32; off >= 1; off >>= 1) {
    lv += __shfl_xor(lv, off);
    kv += __shfl_xor(kv, off);
  }
  __shared__ float slv[4], skv[4];
  const int lane = threadIdx.x & 63, wv = threadIdx.x >> 6;
  if (lane == 0) {
    slv[wv] = lv;
    skv[wv] = kv;
  }
  __syncthreads();
  if (threadIdx.x == 0) {
    atomicAdd(&sums[0], slv[0] + slv[1] + slv[2] + slv[3]);
    atomicAdd(&sums[1], skv[0] + skv[1] + skv[2] + skv[3]);
  }
}

__global__ void k_final(const float* __restrict__ sums,
                        float* __restrict__ out) {
  out[0] = sums[0] / fmaxf(sums[1], 1.0f);
}

extern "C" void kernel_launch(void* const* d_in, const int* in_sizes, int n_in,
                              void* d_out, int out_size, void* d_ws,
                              size_t ws_size, hipStream_t stream) {
  const float* feat = (const float*)d_in[0];
  const int* labels = (const int*)d_in[1];
  const float* ious = (const float*)d_in[2];
  float* out = (float*)d_out;
  char* ws = (char*)d_ws;
  unsigned short* fb16 = (unsigned short*)(ws + FB16_OFF);
  float* rn2 = (float*)(ws + RN2_OFF);
  float* ps = (float*)(ws + PS_OFF);
  int* cnt = (int*)(ws + CNT_OFF);
  float* sums = (float*)(ws + SUM_OFF);

  hipLaunchKernelGGL(k_hist, dim3(1), dim3(256), 0, stream, labels, cnt, sums);
  hipLaunchKernelGGL(k_convert, dim3(M_ROWS / 8), dim3(256), 0, stream, feat,
                     fb16, rn2);
  hipLaunchKernelGGL(k_main, dim3(NRB2 * NCHUNK), dim3(256), 0, stream, fb16,
                     labels, rn2, ps);
  hipLaunchKernelGGL(k_merge, dim3(M_ROWS / 256), dim3(256), 0, stream, ps,
                     cnt, labels, ious, sums);
  hipLaunchKernelGGL(k_final, dim3(1), dim3(1), 0, stream, sums, out);
}

// Round 4
// 36.456 us; speedup vs baseline: 2.9325x; 1.0254x over previous
//
#include <hip/hip_runtime.h>
#include <hip/hip_bf16.h>

// Problem constants (fixed by the reference).
#define M_ROWS 8192
#define K_DIM 128
#define NBINS 64           // label bins (labels 0..19; padded pow2, masked)
#define NCHUNK 8           // column-range splits across the grid
#define NRB2 64            // M / 128 row-blocks
#define TILES_PER_CHUNK 8  // 1024-col chunk / 128-col tiles
#define NPART (NCHUNK * 2) // partial sums per row: chunks x 2 col-waves

// C = 5 * log2(e): score in log2 domain is acc * C. exp(sim - m) = exp2(acc*C - m2).
#define C_LOG2 7.213475204444817f
#define INV_C 0.1386294361119891f
#define FLUSH_THR 160.0f  // exp2(x) == +0.0f for x < -150; 160 adds margin

typedef __attribute__((ext_vector_type(8))) short bf16x8;
typedef __attribute__((ext_vector_type(16))) float f32x16;

// Workspace layout (bytes).
#define FB16_OFF 0
#define RN2_OFF (M_ROWS * K_DIM * 2)         // 2 MB bf16 features
#define PS_OFF (RN2_OFF + M_ROWS * 4)        // +32 KB row-seed (log2 domain)
#define CNT_OFF (PS_OFF + NPART * M_ROWS * 4)
#define SUM_OFF (CNT_OFF + NBINS * 4)
#define DONE_OFF (SUM_OFF + 2 * 4)

__device__ __forceinline__ unsigned short f2bf(float f) {
  union { float f; unsigned int u; } v;
  v.f = f;
  unsigned int r = v.u + 0x7FFFu + ((v.u >> 16) & 1u);  // RNE
  return (unsigned short)(r >> 16);
}

__device__ __forceinline__ void gload_lds16(const unsigned short* g,
                                            unsigned short* l) {
  __builtin_amdgcn_global_load_lds(
      (const __attribute__((address_space(1))) void*)g,
      (__attribute__((address_space(3))) void*)l, 16, 0, 0);
}

// f32 -> bf16 convert fused with row-norm seed rn2[i] = C * ||f_i||^2.
// Block 0 additionally zeroes cnt/sums/done (runs first on the stream; nothing
// reads them until k_hist / k_merge).
__global__ __launch_bounds__(256) void k_convert(const float* __restrict__ src,
                                                 unsigned short* __restrict__ dst,
                                                 float* __restrict__ rn2,
                                                 int* __restrict__ cnt,
                                                 float* __restrict__ sums,
                                                 unsigned int* __restrict__ done) {
  if (blockIdx.x == 0) {
    const int t = threadIdx.x;
    if (t < NBINS) cnt[t] = 0;
    if (t >= NBINS && t < NBINS + 2) sums[t - NBINS] = 0.f;
    if (t == NBINS + 2) *done = 0u;
  }
  const int wid = threadIdx.x >> 6;
  const int lane = threadIdx.x & 63;
  const int half = lane >> 5;
  const int l5 = lane & 31;
  const int row = blockIdx.x * 8 + wid * 2 + half;
  const int base = row * K_DIM + l5 * 4;
  const float4 v = *reinterpret_cast<const float4*>(&src[base]);
  ushort4 o;
  o.x = f2bf(v.x);
  o.y = f2bf(v.y);
  o.z = f2bf(v.z);
  o.w = f2bf(v.w);
  *reinterpret_cast<ushort4*>(&dst[base]) = o;
  float sq = v.x * v.x + v.y * v.y + v.z * v.z + v.w * v.w;
  sq += __shfl_xor(sq, 1);
  sq += __shfl_xor(sq, 2);
  sq += __shfl_xor(sq, 4);
  sq += __shfl_xor(sq, 8);
  sq += __shfl_xor(sq, 16);
  if (l5 == 0) rn2[row] = sq * C_LOG2;
}

// Parallel label histogram: 32 blocks, LDS pre-reduce, global atomic merge.
__global__ __launch_bounds__(256) void k_hist(const int* __restrict__ labels,
                                              int* __restrict__ cnt) {
  __shared__ int h[NBINS];
  const int t = threadIdx.x;
  if (t < NBINS) h[t] = 0;
  __syncthreads();
  const int i = blockIdx.x * 256 + t;
  atomicAdd(&h[labels[i] & (NBINS - 1)], 1);
  __syncthreads();
  if (t < NBINS && h[t]) atomicAdd(&cnt[t], h[t]);
}

// Fused sim + masked exp-sum, LDS-staged B (2-phase double buffer), 32x32x16
// MFMA. Block = 4 waves (2 row x 2 col); block tile = 128 rows x 128 cols per
// step; wave tile = 64x64 as 2x2 32x32 MFMAs x 8 K-steps. Grid = 64x8 = 512.
//
// LDS B-tile layout: logical (col, slot) [slot = 16B k-chunk, 16/row] stored
// at byte col*256 + (slot ^ (col&7))*16; staged with linear LDS dest +
// inverse-swizzled GLOBAL source, read back with the same XOR (rule 21).
__global__ __launch_bounds__(256, 2) void k_main(
    const unsigned short* __restrict__ fb16, const int* __restrict__ labels,
    const float* __restrict__ rn2, float* __restrict__ ps) {
  __shared__ unsigned short lds[2][128 * 128];  // 2 x 32 KB

  const int tid = threadIdx.x;
  const int lane = tid & 63;
  const int wid = tid >> 6;
  const int wr = wid >> 1;
  const int wc = wid & 1;
  const int rb = (int)blockIdx.x % NRB2;
  const int chunk = (int)blockIdx.x / NRB2;
  const int l15 = lane & 15;
  const int lhi = lane >> 4;
  const int l31 = lane & 31;
  const int lh32 = lane >> 5;
  const int row0 = rb * 128 + wr * 64;
  const int col0 = chunk * 1024;

  // A fragments (32x32x16): lane holds A[l&31][(l>>5)*8 + e] per k-slice.
  bf16x8 a[2][8];
#pragma unroll
  for (int ri = 0; ri < 2; ++ri) {
    const int row = row0 + ri * 32 + l31;
#pragma unroll
    for (int ks = 0; ks < 8; ++ks)
      a[ri][ks] = *reinterpret_cast<const bf16x8*>(
          &fb16[row * K_DIM + ks * 16 + lh32 * 8]);
  }

  // Flush threshold (acc domain): if every acc < (min rn2 - 160)/C over the
  // wave's 64 rows, all exp2 terms are exact +0.0f. One load + 6-step min.
  float thrMin = rn2[row0 + lane];
  thrMin = fminf(thrMin, __shfl_xor(thrMin, 1));
  thrMin = fminf(thrMin, __shfl_xor(thrMin, 2));
  thrMin = fminf(thrMin, __shfl_xor(thrMin, 4));
  thrMin = fminf(thrMin, __shfl_xor(thrMin, 8));
  thrMin = fminf(thrMin, __shfl_xor(thrMin, 16));
  thrMin = fminf(thrMin, __shfl_xor(thrMin, 32));
  const float thrAcc = (thrMin - FLUSH_THR) * INV_C;

  float s_st[2][16];
#pragma unroll
  for (int ri = 0; ri < 2; ++ri)
#pragma unroll
    for (int r = 0; r < 16; ++r) s_st[ri][r] = 0.f;

  // Staging: one 128x128 B-tile = 32 instr (8 per wave), 1 KB each.
#define STAGE(buf, t)                                                        \
  {                                                                          \
    const int colT_ = col0 + (t) * 128;                                      \
    _Pragma("unroll") for (int it = 0; it < 8; ++it) {                       \
      const int col_ = wid * 32 + it * 4 + lhi;                              \
      const int crow_ = colT_ + col_;                                        \
      gload_lds16(&fb16[crow_ * K_DIM + ((l15 ^ (col_ & 7)) << 3)],          \
                  &lds[buf][wid * 4096 + it * 512]);                         \
    }                                                                        \
  }

  STAGE(0, 0);
  asm volatile("s_waitcnt vmcnt(0)" ::: "memory");
  __builtin_amdgcn_s_barrier();

  int cur = 0;
#pragma unroll
  for (int t = 0; t < TILES_PER_CHUNK; ++t) {
    if (t < TILES_PER_CHUNK - 1) STAGE(cur ^ 1, t + 1);

    f32x16 acc[2][2];
#pragma unroll
    for (int ri = 0; ri < 2; ++ri)
#pragma unroll
      for (int cj = 0; cj < 2; ++cj)
#pragma unroll
        for (int e = 0; e < 16; ++e) acc[ri][cj][e] = 0.f;

    const unsigned short* bufp = &lds[cur][0];
#pragma unroll
    for (int ks = 0; ks < 8; ++ks) {
      bf16x8 b[2];
#pragma unroll
      for (int cj = 0; cj < 2; ++cj) {
        const int col = wc * 64 + cj * 32 + l31;
        const int phys = (ks * 2 + lh32) ^ (col & 7);
        b[cj] = *reinterpret_cast<const bf16x8*>(&bufp[col * 128 + phys * 8]);
      }
#pragma unroll
      for (int ri = 0; ri < 2; ++ri)
#pragma unroll
        for (int cj = 0; cj < 2; ++cj)
          acc[ri][cj] = __builtin_amdgcn_mfma_f32_32x32x16_bf16(
              a[ri][ks], b[cj], acc[ri][cj], 0, 0, 0);
    }

    // Per-lane flush test (fmax trees fuse to v_max3; no cross-lane traffic).
    float mx = -INFINITY;
#pragma unroll
    for (int ri = 0; ri < 2; ++ri)
#pragma unroll
      for (int cj = 0; cj < 2; ++cj)
#pragma unroll
        for (int e = 0; e < 16; ++e) mx = fmaxf(mx, acc[ri][cj][e]);

    if (__any(mx >= thrAcc)) {
      // Rare path (diagonal tile): full masked exp2 against fixed row seeds.
      // C/D layout: col = lane&31, row = (r&3) + 8*(r>>2) + 4*(lane>>5).
      const int colT = col0 + t * 128 + wc * 64;
      int clab[2];
#pragma unroll
      for (int cj = 0; cj < 2; ++cj) clab[cj] = labels[colT + cj * 32 + l31];
#pragma unroll
      for (int ri = 0; ri < 2; ++ri) {
#pragma unroll
        for (int p = 0; p < 4; ++p) {
          const int rbase = row0 + ri * 32 + lh32 * 4 + p * 8;
          const float4 ms = *reinterpret_cast<const float4*>(&rn2[rbase]);
          const int4 rl = *reinterpret_cast<const int4*>(&labels[rbase]);
          const float msv[4] = {ms.x, ms.y, ms.z, ms.w};
          const int rlv[4] = {rl.x, rl.y, rl.z, rl.w};
#pragma unroll
          for (int q = 0; q < 4; ++q) {
            const int r = p * 4 + q;
            float pa = 0.f;
#pragma unroll
            for (int cj = 0; cj < 2; ++cj) {
              const float sc2 = acc[ri][cj][r] * C_LOG2 - msv[q];
              pa += (clab[cj] != rlv[q]) ? exp2f(sc2) : 0.f;
            }
            s_st[ri][r] += pa;
          }
        }
      }
    }

    // One barrier per tile: drains this iter's stage and fences buffer reuse.
    asm volatile("s_waitcnt vmcnt(0)" ::: "memory");
    __builtin_amdgcn_s_barrier();
    cur ^= 1;
  }

  // One cross-lane reduction per wave at the end: sum over the 32 lanes
  // (cols) sharing each row; lane l31==0 stores float4 runs.
#pragma unroll
  for (int ri = 0; ri < 2; ++ri)
#pragma unroll
    for (int r = 0; r < 16; ++r) {
      float p = s_st[ri][r];
      p += __shfl_xor(p, 1);
      p += __shfl_xor(p, 2);
      p += __shfl_xor(p, 4);
      p += __shfl_xor(p, 8);
      p += __shfl_xor(p, 16);
      s_st[ri][r] = p;
    }
  if (l31 == 0) {
    const int part = chunk * 2 + wc;
#pragma unroll
    for (int ri = 0; ri < 2; ++ri)
#pragma unroll
      for (int p = 0; p < 4; ++p) {
        float4 v = {s_st[ri][p * 4 + 0], s_st[ri][p * 4 + 1],
                    s_st[ri][p * 4 + 2], s_st[ri][p * 4 + 3]};
        *reinterpret_cast<float4*>(
            &ps[part * M_ROWS + row0 + ri * 32 + lh32 * 4 + p * 8]) = v;
      }
  }
}

// Merge partials -> per-row loss -> global sums; last block finalizes the
// scalar (device-scope atomics + done counter; all state zeroed per call).
__global__ __launch_bounds__(256) void k_merge(
    const float* __restrict__ ps, const int* __restrict__ cnt,
    const int* __restrict__ labels, const float* __restrict__ ious,
    float* __restrict__ sums, unsigned int* __restrict__ done,
    float* __restrict__ out) {
  const int row = blockIdx.x * 256 + threadIdx.x;
  float ns = 0.f;
#pragma unroll
  for (int p = 0; p < NPART; ++p) ns += ps[p * M_ROWS + row];
  int pc = cnt[labels[row] & (NBINS - 1)] - 1;
  if (pc < 1) pc = 1;  // reference always has pos_cnt >= 1 here; avoid 0/0
  const float loss = ns / (float)pc;  // LAMDA = 1; loss = -log_prob
  const bool keep = ious[row] >= 0.5f;
  float lv = keep ? loss : 0.f;
  float kv = keep ? 1.f : 0.f;
#pragma unroll
  for (int off = 32; off >= 1; off >>= 1) {
    lv += __shfl_xor(lv, off);
    kv += __shfl_xor(kv, off);
  }
  __shared__ float slv[4], skv[4];
  const int lane = threadIdx.x & 63, wv = threadIdx.x >> 6;
  if (lane == 0) {
    slv[wv] = lv;
    skv[wv] = kv;
  }
  __syncthreads();
  if (threadIdx.x == 0) {
    atomicAdd(&sums[0], slv[0] + slv[1] + slv[2] + slv[3]);
    atomicAdd(&sums[1], skv[0] + skv[1] + skv[2] + skv[3]);
    __threadfence();
    const unsigned int old = atomicAdd(done, 1u);
    if (old == (unsigned int)(M_ROWS / 256 - 1)) {
      const float a = atomicAdd(&sums[0], 0.f);  // atomic read (L2-coherent)
      const float b = atomicAdd(&sums[1], 0.f);
      out[0] = a / fmaxf(b, 1.f);
    }
  }
}

extern "C" void kernel_launch(void* const* d_in, const int* in_sizes, int n_in,
                              void* d_out, int out_size, void* d_ws,
                              size_t ws_size, hipStream_t stream) {
  const float* feat = (const float*)d_in[0];
  const int* labels = (const int*)d_in[1];
  const float* ious = (const float*)d_in[2];
  float* out = (float*)d_out;
  char* ws = (char*)d_ws;
  unsigned short* fb16 = (unsigned short*)(ws + FB16_OFF);
  float* rn2 = (float*)(ws + RN2_OFF);
  float* ps = (float*)(ws + PS_OFF);
  int* cnt = (int*)(ws + CNT_OFF);
  float* sums = (float*)(ws + SUM_OFF);
  unsigned int* done = (unsigned int*)(ws + DONE_OFF);

  hipLaunchKernelGGL(k_convert, dim3(M_ROWS / 8), dim3(256), 0, stream, feat,
                     fb16, rn2, cnt, sums, done);
  hipLaunchKernelGGL(k_hist, dim3(M_ROWS / 256), dim3(256), 0, stream, labels,
                     cnt);
  hipLaunchKernelGGL(k_main, dim3(NRB2 * NCHUNK), dim3(256), 0, stream, fb16,
                     labels, rn2, ps);
  hipLaunchKernelGGL(k_merge, dim3(M_ROWS / 256), dim3(256), 0, stream, ps,
                     cnt, labels, ious, sums, done, out);
}